// Round 7
// baseline (200.390 us; speedup 1.0000x reference)
//
#include <hip/hip_runtime.h>

// Problem constants (from reference setup_inputs): B=128, Q=500, C=80, T=64
#define BN 128
#define QN 500
#define CLS 80
#define TN 64
#define WAVES 16               // waves per block in the fused kernel

typedef unsigned long long ull;

// Monotonic float->uint map: a < b  <=>  fkey(a) < fkey(b); equal <=> equal
__device__ __forceinline__ unsigned fkey(float x) {
    unsigned u = __float_as_uint(x);
    return (u & 0x80000000u) ? ~u : (u | 0x80000000u);
}
__device__ __forceinline__ ull umin64(ull a, ull b) { return a < b ? a : b; }
// maintain t1 < t2 = two smallest of a set of DISTINCT keys
__device__ __forceinline__ void ins2(ull& t1, ull& t2, ull x) {
    if (x < t1) { t2 = t1; t1 = x; }
    else if (x < t2) { t2 = x; }
}

// ---------------------------------------------------------------------------
// Fused kernel: one block per image (1024 threads = 16 waves).
// Phase 1 (all 16 waves): compute cost rows q = wave, wave+16, ... (31-32
//   rows each); lane = column t. Math is EXACTLY the round-4/6 formulation
//   (expf/log1pf/logf + true divisions) -- fast-math perturbs ties and
//   cascades through the sequential greedy (round-5 failure). While
//   computing, each wave keeps per-column TOP-2 u64 keys (fkey<<32|flat) in
//   registers -> the 16.4 MB matrix is never re-read and no workspace is
//   needed (round 6 showed ws_size < 640 KB: fallback FETCH ~= 8 MB).
// Phase 2 (wave 0): greedy assignment on column state. m1[j] = alive-min of
//   column j, m2[j] = runner-up. u64 radix-4 butterfly = exact raveled
//   argmin incl. first-occurrence tie-break. Champion-row death promotes
//   m2 in-register (exact: any alive key < m2 could only be m1); cooperative
//   top-2 rescan only when both are dead (expected ~1-3 per image).
// ---------------------------------------------------------------------------
__global__ __launch_bounds__(1024, 1) void fused_kernel(
    const float* __restrict__ logits,   // [B,Q,C]
    const float* __restrict__ boxes,    // [B,Q,4]
    const int*   __restrict__ ids,      // [B,T]
    const float* __restrict__ tboxes,   // [B,T,4]
    const float* __restrict__ img,      // [B,4]
    float* __restrict__ Cout,           // [B,Q,T]
    float* __restrict__ out_rows,       // [B,T] (as f32 values)
    float* __restrict__ out_cols)       // [B,T]
{
    const int b    = blockIdx.x;
    const int wave = threadIdx.x >> 6;
    const int lane = threadIdx.x & 63;   // = column t
    float* __restrict__ Cb = Cout + (size_t)b * QN * TN;

    // per-lane constants (hoisting matches reference: tn computed per target)
    const float4 tb = *(const float4*)(tboxes + (size_t)(b * TN + lane) * 4);
    const float4 im = *(const float4*)(img + b * 4);
    const int    id = ids[b * TN + lane];
    const float tnx = tb.x / im.x, tny = tb.y / im.y;
    const float tnz = tb.z / im.z, tnw = tb.w / im.w;
    const float area_b = (tb.z - tb.x) * (tb.w - tb.y);

    // ---- phase 1: cost rows + per-wave per-column top-2
    ull m1 = ~0ull, m2 = ~0ull;
    for (int q = wave; q < QN; q += WAVES) {
        const float4 pb = *(const float4*)(boxes + (size_t)(b * QN + q) * 4);
        const float x   = logits[(size_t)(b * QN + q) * CLS + id];

        // focal-style class cost (round-4 exact ops/order)
        float prob = 1.0f / (1.0f + expf(-x));
        float neg  = 0.75f * (prob * prob) * (-log1pf(1e-8f - prob));
        float pos  = 0.25f * ((1.0f - prob) * (1.0f - prob)) * (-logf(prob + 1e-8f));
        float cls  = pos - neg;

        // L1 on normalized boxes (true divisions, round-4 exact)
        float l1 = fabsf(pb.x / im.x - tnx) + fabsf(pb.y / im.y - tny)
                 + fabsf(pb.z / im.z - tnz) + fabsf(pb.w / im.w - tnw);

        // GIoU on pixel boxes (round-4 exact)
        float area_a = (pb.z - pb.x) * (pb.w - pb.y);
        float ltx = fmaxf(pb.x, tb.x), lty = fmaxf(pb.y, tb.y);
        float rbx = fminf(pb.z, tb.z), rby = fminf(pb.w, tb.w);
        float iw = fmaxf(rbx - ltx, 0.0f), ih = fmaxf(rby - lty, 0.0f);
        float inter = iw * ih;
        float uni   = area_a + area_b - inter;
        float iou   = inter / uni;
        float ex1 = fminf(pb.x, tb.x), ey1 = fminf(pb.y, tb.y);
        float ex2 = fmaxf(pb.z, tb.z), ey2 = fmaxf(pb.w, tb.w);
        float ew = fmaxf(ex2 - ex1, 0.0f), eh = fmaxf(ey2 - ey1, 0.0f);
        float enc = ew * eh;
        float giou = iou - (enc - uni) / enc;

        float cost = 5.0f * l1 + 2.0f * cls + 2.0f * (-giou);
        Cb[(size_t)q * TN + lane] = cost;

        ins2(m1, m2, ((ull)fkey(cost) << 32) | (unsigned)(q * TN + lane));
    }

    // ---- merge 16 waves' top-2 through LDS
    __shared__ ull lds1[WAVES][TN];
    __shared__ ull lds2[WAVES][TN];
    lds1[wave][lane] = m1;
    lds2[wave][lane] = m2;
    __syncthreads();
    if (wave != 0) return;               // greedy is single-wave

    m1 = ~0ull; m2 = ~0ull;
    #pragma unroll
    for (int w = 0; w < WAVES; ++w) {
        ins2(m1, m2, lds1[w][lane]);
        ins2(m1, m2, lds2[w][lane]);
    }

    // row-dead bitmask (wave-uniform values, static indices); rows 500..511
    // (rescan over-range) pre-marked dead.
    ull rowdead[8];
    #pragma unroll
    for (int w = 0; w < 8; ++w) rowdead[w] = 0ull;
    rowdead[7] = 0xFFF0000000000000ull;

    int my_i = 0, my_j = 0;              // lane t captures iteration t's result

    for (int t = 0; t < TN; ++t) {
        // --- exact global argmin: u64 radix-4 butterfly, straight-line
        ull best = m1;
        #pragma unroll
        for (int s = 0; s < 3; ++s) {
            const int o = 1 << (2 * s);
            ull b0 = __shfl_xor(best, o);
            ull b1 = __shfl_xor(best, 2 * o);
            ull b2 = __shfl_xor(best, 3 * o);
            best = umin64(umin64(best, b0), umin64(b1, b2));
        }
        const unsigned flat = __builtin_amdgcn_readfirstlane((unsigned)best);
        const int i = (int)(flat >> 6);
        const int j = (int)(flat & 63u);
        if (lane == t) { my_i = i; my_j = j; }

        // retire winning column, then winning row
        if (lane == j) { m1 = ~0ull; m2 = ~0ull; }
        #pragma unroll
        for (int w = 0; w < 8; ++w)
            if ((i >> 6) == w) rowdead[w] |= (1ull << (i & 63));

        // champion death -> promote runner-up if its row is alive, else rescan.
        // INF keys: flat=0xFFFFFFFF -> argrow 0x3FFFFFF never matches i.
        bool needscan = false;
        if ((((unsigned)m1) >> 6) == (unsigned)i) {
            const unsigned r2 = ((unsigned)m2) >> 6;     // runner-up row
            const unsigned w2 = r2 >> 6;
            ull word = ~0ull;                            // default: dead
            #pragma unroll
            for (int w = 0; w < 8; ++w)
                if (w2 == (unsigned)w) word = rowdead[w];
            const bool alive = !((word >> (r2 & 63u)) & 1ull);
            if (alive) { m1 = m2; m2 = ~0ull; }          // exact promotion
            else       { needscan = true; m1 = ~0ull; }
        }

        ull need = __ballot(needscan);
        while (need) {                                   // rare (~1-3/image)
            const int jr = (int)(__ffsll((long long)need) - 1);  // lane==column
            need &= need - 1;
            // cooperative top-2 over alive rows of column jr
            ull b1k = ~0ull, b2k = ~0ull;
            #pragma unroll
            for (int k8 = 0; k8 < 8; ++k8) {
                int r = lane + (k8 << 6);   // rows 500..511 dead-masked;
                                            // reads stay inside d_out buffer
                float vv = Cb[(size_t)r * TN + jr];
                bool dead = (rowdead[k8] >> lane) & 1ull;
                ull kk = dead ? ~0ull
                              : (((ull)fkey(vv) << 32) | (unsigned)(r * TN + jr));
                ins2(b1k, b2k, kk);
            }
            #pragma unroll
            for (int off = 1; off < 64; off <<= 1) {
                ull o1 = __shfl_xor(b1k, off);
                ull o2 = __shfl_xor(b2k, off);
                ins2(b1k, b2k, o1);
                ins2(b1k, b2k, o2);
            }
            if (lane == jr) { m1 = b1k; m2 = b2k; }
        }
    }

    // coalesced index write: lane t holds iteration t's (i,j)
    out_rows[b * TN + lane] = (float)my_i;
    out_cols[b * TN + lane] = (float)my_j;
}

extern "C" void kernel_launch(void* const* d_in, const int* in_sizes, int n_in,
                              void* d_out, int out_size, void* d_ws, size_t ws_size,
                              hipStream_t stream) {
    const float* logits = (const float*)d_in[0];   // [128,500,80]
    const float* boxes  = (const float*)d_in[1];   // [128,500,4]
    const int*   ids    = (const int*)d_in[2];     // [128,64]
    const float* tboxes = (const float*)d_in[3];   // [128,64,4]
    const float* img    = (const float*)d_in[4];   // [128,4]

    float* out  = (float*)d_out;
    float* Cmat = out;                              // 128*500*64 = 4,096,000
    float* rows = out + (size_t)BN * QN * TN;       // +8192
    float* cols = rows + BN * TN;                   // +8192

    fused_kernel<<<BN, WAVES * 64, 0, stream>>>(logits, boxes, ids, tboxes, img,
                                                Cmat, rows, cols);
}

// Round 8
// 191.933 us; speedup vs baseline: 1.0441x; 1.0441x over previous
//
#include <hip/hip_runtime.h>

// Problem constants (from reference setup_inputs): B=128, Q=500, C=80, T=64
#define BN 128
#define QN 500
#define CLS 80
#define TN 64
#define RPB 50                  // rows per cost block
#define CBI 10                  // cost blocks per image (500/50)

typedef unsigned long long ull;

// Monotonic float->uint map: a < b  <=>  fkey(a) < fkey(b); equal <=> equal
__device__ __forceinline__ unsigned fkey(float x) {
    unsigned u = __float_as_uint(x);
    return (u & 0x80000000u) ? ~u : (u | 0x80000000u);
}
// maintain t1 < t2 = two smallest of a set of DISTINCT keys
__device__ __forceinline__ void ins2(ull& t1, ull& t2, ull x) {
    if (x < t1) { t2 = t1; t1 = x; }
    else if (x < t2) { t2 = x; }
}

// Full-wave (64-lane) u32 min via DPP: row_shr 1/2/4/8 + row_bcast15/31,
// identity 0xFFFFFFFF fed to invalid lanes; result in lane 63 -> readlane.
// ~6 dependent VALU pairs (~50 cyc) vs ~240+ for a ds_bpermute butterfly.
#define DPP_MIN_STEP(v, ctrl)                                                 \
    {                                                                         \
        unsigned _t = (unsigned)__builtin_amdgcn_update_dpp(                  \
            (int)0xFFFFFFFF, (int)(v), (ctrl), 0xf, 0xf, false);              \
        (v) = (_t < (v)) ? _t : (v);                                          \
    }
__device__ __forceinline__ unsigned wave_min_u32(unsigned v) {
    DPP_MIN_STEP(v, 0x111)   // row_shr:1
    DPP_MIN_STEP(v, 0x112)   // row_shr:2
    DPP_MIN_STEP(v, 0x114)   // row_shr:4
    DPP_MIN_STEP(v, 0x118)   // row_shr:8
    DPP_MIN_STEP(v, 0x142)   // row_bcast:15
    DPP_MIN_STEP(v, 0x143)   // row_bcast:31
    return (unsigned)__builtin_amdgcn_readlane((int)v, 63);
}

// ---------------------------------------------------------------------------
// Kernel 1: cost matrix — BYTE-IDENTICAL math to round 4/6 (expf, log1pf,
// logf, true divisions). Fast-math variants perturb costs ~1e-4 which flips
// argmin ties and cascades through the sequential greedy (round-5 failure).
// 1280 blocks (10/image) x 256 threads saturate all 256 CUs (round-7 fusion
// put this phase on 128 CUs and regressed 154->200 us).
// ---------------------------------------------------------------------------
__global__ __launch_bounds__(256) void cost_kernel(
    const float* __restrict__ logits,   // [B,Q,C]
    const float* __restrict__ boxes,    // [B,Q,4]
    const int*   __restrict__ ids,      // [B,T]
    const float* __restrict__ tboxes,   // [B,T,4]
    const float* __restrict__ img,      // [B,4]
    float* __restrict__ Cout)           // [B,Q,T]
{
    const int b    = blockIdx.x / CBI;
    const int blk  = blockIdx.x % CBI;
    const int q0   = blk * RPB;
    const int wave = threadIdx.x >> 6;
    const int lane = threadIdx.x & 63;   // = column t

    const float4 tb = *(const float4*)(tboxes + (size_t)(b * TN + lane) * 4);
    const float4 im = *(const float4*)(img + b * 4);
    const int    id = ids[b * TN + lane];
    const float tnx = tb.x / im.x, tny = tb.y / im.y;
    const float tnz = tb.z / im.z, tnw = tb.w / im.w;
    const float area_b = (tb.z - tb.x) * (tb.w - tb.y);

    for (int r = wave; r < RPB; r += 4) {
        const int q = q0 + r;
        const float4 pb = *(const float4*)(boxes + (size_t)(b * QN + q) * 4);
        const float x   = logits[(size_t)(b * QN + q) * CLS + id];

        float prob = 1.0f / (1.0f + expf(-x));
        float neg  = 0.75f * (prob * prob) * (-log1pf(1e-8f - prob));
        float pos  = 0.25f * ((1.0f - prob) * (1.0f - prob)) * (-logf(prob + 1e-8f));
        float cls  = pos - neg;

        float l1 = fabsf(pb.x / im.x - tnx) + fabsf(pb.y / im.y - tny)
                 + fabsf(pb.z / im.z - tnz) + fabsf(pb.w / im.w - tnw);

        float area_a = (pb.z - pb.x) * (pb.w - pb.y);
        float ltx = fmaxf(pb.x, tb.x), lty = fmaxf(pb.y, tb.y);
        float rbx = fminf(pb.z, tb.z), rby = fminf(pb.w, tb.w);
        float iw = fmaxf(rbx - ltx, 0.0f), ih = fmaxf(rby - lty, 0.0f);
        float inter = iw * ih;
        float uni   = area_a + area_b - inter;
        float iou   = inter / uni;
        float ex1 = fminf(pb.x, tb.x), ey1 = fminf(pb.y, tb.y);
        float ex2 = fmaxf(pb.z, tb.z), ey2 = fmaxf(pb.w, tb.w);
        float ew = fmaxf(ex2 - ex1, 0.0f), eh = fmaxf(ey2 - ey1, 0.0f);
        float enc = ew * eh;
        float giou = iou - (enc - uni) / enc;

        Cout[(size_t)(b * QN + q) * TN + lane] = 5.0f * l1 + 2.0f * cls + 2.0f * (-giou);
    }
}

// ---------------------------------------------------------------------------
// Kernel 2: greedy assignment, TOP-2 column state + DPP reductions.
// Lane j of wave 0 holds column j's two smallest alive u64 keys (m1 < m2),
// key = (fkey<<32 | flat). Global argmin per iteration: DPP u32-min on the
// value half, then DPP u32-min on flat among value-candidates -> exact
// raveled-argmin incl. first-occurrence tie-break, no LDS/bpermute in the
// common path. Champion-row death promotes m2 in-register when m2's row is
// alive (exact: only m1 could be a smaller alive key); cooperative rescan
// only on double-death (rare). Init: 8 waves x 63 fixed-trip coalesced rows.
// ---------------------------------------------------------------------------
__global__ __launch_bounds__(512, 1) void assign_kernel(
    const float* __restrict__ Cmat,     // [B,Q,T]
    float* __restrict__ out_rows,       // [B,T] (as f32 values)
    float* __restrict__ out_cols)       // [B,T]
{
    const int b    = blockIdx.x;
    const int wave = threadIdx.x >> 6;
    const int lane = threadIdx.x & 63;   // = column
    const float* Cb = Cmat + (size_t)b * QN * TN;

    __shared__ ull lds1[8][TN];
    __shared__ ull lds2[8][TN];

    // ---- init: wave w scans rows [w*63, w*63+63); fixed trip -> unrolled,
    // loads pipelined. Rows 500..503 (wave 7 tail) read in-bounds garbage
    // from the rows-output region and are key-masked to INF.
    {
        ull m1 = ~0ull, m2 = ~0ull;
        const int rbeg = wave * 63;
        #pragma unroll
        for (int rr = 0; rr < 63; ++rr) {
            const int r = rbeg + rr;    // <= 503: inside d_out buffer
            float v = Cb[(size_t)r * TN + lane];
            ull kk = (r < QN) ? (((ull)fkey(v) << 32) | (unsigned)(r * TN + lane))
                              : ~0ull;
            ins2(m1, m2, kk);
        }
        lds1[wave][lane] = m1;
        lds2[wave][lane] = m2;
    }
    __syncthreads();
    if (wave != 0) return;              // hot loop is single-wave

    ull m1 = ~0ull, m2 = ~0ull;
    #pragma unroll
    for (int w = 0; w < 8; ++w) {
        ins2(m1, m2, lds1[w][lane]);
        ins2(m1, m2, lds2[w][lane]);
    }

    // row-dead bitmask (wave-uniform values, static indices); rows 500..511
    // (rescan over-range) pre-marked dead.
    ull rowdead[8];
    #pragma unroll
    for (int w = 0; w < 8; ++w) rowdead[w] = 0ull;
    rowdead[7] = 0xFFF0000000000000ull;

    int my_i = 0, my_j = 0;             // lane t captures iteration t's result

    for (int t = 0; t < TN; ++t) {
        // --- exact global argmin via two DPP reductions
        const unsigned hi = (unsigned)(m1 >> 32);
        const unsigned bv = wave_min_u32(hi);               // min value (uniform)
        const unsigned fl = (hi == bv) ? (unsigned)m1 : 0xFFFFFFFFu;
        const unsigned flat = wave_min_u32(fl);             // min flat among ties
        const int i = (int)(flat >> 6);
        const int j = (int)(flat & 63u);
        if (lane == t) { my_i = i; my_j = j; }

        // retire winning column, then winning row
        if (lane == j) { m1 = ~0ull; m2 = ~0ull; }
        #pragma unroll
        for (int w = 0; w < 8; ++w)
            if ((i >> 6) == w) rowdead[w] |= (1ull << (i & 63));

        // champion death -> promote runner-up if its row is alive, else rescan.
        // INF keys: flat=0xFFFFFFFF -> argrow 0x3FFFFFF never matches i.
        bool needscan = false;
        if ((((unsigned)m1) >> 6) == (unsigned)i) {
            const unsigned r2 = ((unsigned)m2) >> 6;        // runner-up row
            const unsigned w2 = r2 >> 6;
            ull word = ~0ull;                               // default: dead
            #pragma unroll
            for (int w = 0; w < 8; ++w)
                if (w2 == (unsigned)w) word = rowdead[w];
            const bool alive = !((word >> (r2 & 63u)) & 1ull);
            if (alive) { m1 = m2; m2 = ~0ull; }             // exact promotion
            else       { needscan = true; m1 = ~0ull; }
        }

        ull need = __ballot(needscan);
        while (need) {                                      // rare (~1-3/image)
            const int jr = (int)(__ffsll((long long)need) - 1);  // lane==column
            need &= need - 1;
            // cooperative top-2 over alive rows of column jr
            ull b1k = ~0ull, b2k = ~0ull;
            #pragma unroll
            for (int k8 = 0; k8 < 8; ++k8) {
                int r = lane + (k8 << 6);    // rows 500..511 dead-masked;
                                             // reads stay inside d_out buffer
                float vv = Cb[(size_t)r * TN + jr];
                bool dead = (rowdead[k8] >> lane) & 1ull;
                ull kk = dead ? ~0ull
                              : (((ull)fkey(vv) << 32) | (unsigned)(r * TN + jr));
                ins2(b1k, b2k, kk);
            }
            #pragma unroll
            for (int off = 1; off < 64; off <<= 1) {
                ull o1 = __shfl_xor(b1k, off);
                ull o2 = __shfl_xor(b2k, off);
                ins2(b1k, b2k, o1);
                ins2(b1k, b2k, o2);
            }
            if (lane == jr) { m1 = b1k; m2 = b2k; }
        }
    }

    // coalesced index write: lane t holds iteration t's (i,j)
    out_rows[b * TN + lane] = (float)my_i;
    out_cols[b * TN + lane] = (float)my_j;
}

extern "C" void kernel_launch(void* const* d_in, const int* in_sizes, int n_in,
                              void* d_out, int out_size, void* d_ws, size_t ws_size,
                              hipStream_t stream) {
    const float* logits = (const float*)d_in[0];   // [128,500,80]
    const float* boxes  = (const float*)d_in[1];   // [128,500,4]
    const int*   ids    = (const int*)d_in[2];     // [128,64]
    const float* tboxes = (const float*)d_in[3];   // [128,64,4]
    const float* img    = (const float*)d_in[4];   // [128,4]

    float* out  = (float*)d_out;
    float* Cmat = out;                              // 128*500*64 = 4,096,000
    float* rows = out + (size_t)BN * QN * TN;       // +8192
    float* cols = rows + BN * TN;                   // +8192

    cost_kernel<<<BN * CBI, 256, 0, stream>>>(logits, boxes, ids, tboxes, img, Cmat);
    assign_kernel<<<BN, 512, 0, stream>>>(Cmat, rows, cols);
}

// Round 9
// 146.719 us; speedup vs baseline: 1.3658x; 1.3082x over previous
//
#include <hip/hip_runtime.h>

// Problem constants (from reference setup_inputs): B=128, Q=500, C=80, T=64
#define BN 128
#define QN 500
#define CLS 80
#define TN 64
#define RPB 50                  // rows per cost block
#define CBI 10                  // cost blocks per image (500/50)

typedef unsigned long long ull;

// Monotonic float->uint map: a < b  <=>  fkey(a) < fkey(b); equal <=> equal
__device__ __forceinline__ unsigned fkey(float x) {
    unsigned u = __float_as_uint(x);
    return (u & 0x80000000u) ? ~u : (u | 0x80000000u);
}
__device__ __forceinline__ ull kmin(ull a, ull b) { return a < b ? a : b; }  // branchless

// Full-wave (64-lane) u32 min via DPP: row_shr 1/2/4/8 + row_bcast15/31,
// identity 0xFFFFFFFF fed to invalid lanes; result in lane 63 -> readlane.
#define DPP_MIN_STEP(v, ctrl)                                                 \
    {                                                                         \
        unsigned _t = (unsigned)__builtin_amdgcn_update_dpp(                  \
            (int)0xFFFFFFFF, (int)(v), (ctrl), 0xf, 0xf, false);              \
        (v) = (_t < (v)) ? _t : (v);                                          \
    }
__device__ __forceinline__ unsigned wave_min_u32(unsigned v) {
    DPP_MIN_STEP(v, 0x111)   // row_shr:1
    DPP_MIN_STEP(v, 0x112)   // row_shr:2
    DPP_MIN_STEP(v, 0x114)   // row_shr:4
    DPP_MIN_STEP(v, 0x118)   // row_shr:8
    DPP_MIN_STEP(v, 0x142)   // row_bcast:15
    DPP_MIN_STEP(v, 0x143)   // row_bcast:31
    return (unsigned)__builtin_amdgcn_readlane((int)v, 63);
}

// ---------------------------------------------------------------------------
// Table init: 64 KB of ~0ull (u64-min identity). Runs every call (d_ws is
// re-poisoned 0xAA by the harness, and 0xAAAA.. is NOT > all real keys).
// ---------------------------------------------------------------------------
__global__ void table_init_kernel(ull* __restrict__ table) {
    int idx = blockIdx.x * blockDim.x + threadIdx.x;   // grid sized exactly
    table[idx] = ~0ull;
}

// ---------------------------------------------------------------------------
// Kernel 1: cost matrix — math BYTE-IDENTICAL to rounds 4/6/8 (expf, log1pf,
// logf, true divisions). Fast-math perturbs ties -> cascades through the
// sequential greedy (round-5 failure). 1280 blocks saturate all 256 CUs.
// NEW: tracks per-column min key (branchless) and atomicMin's one entry per
// column per block into the d_ws table (associative -> exact global min).
// ---------------------------------------------------------------------------
__global__ __launch_bounds__(256) void cost_kernel(
    const float* __restrict__ logits,   // [B,Q,C]
    const float* __restrict__ boxes,    // [B,Q,4]
    const int*   __restrict__ ids,      // [B,T]
    const float* __restrict__ tboxes,   // [B,T,4]
    const float* __restrict__ img,      // [B,4]
    float* __restrict__ Cout,           // [B,Q,T]
    ull* __restrict__ table)            // [B,T] colmin keys, or null
{
    const int b    = blockIdx.x / CBI;
    const int blk  = blockIdx.x % CBI;
    const int q0   = blk * RPB;
    const int wave = threadIdx.x >> 6;
    const int lane = threadIdx.x & 63;   // = column t

    const float4 tb = *(const float4*)(tboxes + (size_t)(b * TN + lane) * 4);
    const float4 im = *(const float4*)(img + b * 4);
    const int    id = ids[b * TN + lane];
    const float tnx = tb.x / im.x, tny = tb.y / im.y;
    const float tnz = tb.z / im.z, tnw = tb.w / im.w;
    const float area_b = (tb.z - tb.x) * (tb.w - tb.y);

    ull colmin = ~0ull;
    for (int r = wave; r < RPB; r += 4) {
        const int q = q0 + r;
        const float4 pb = *(const float4*)(boxes + (size_t)(b * QN + q) * 4);
        const float x   = logits[(size_t)(b * QN + q) * CLS + id];

        float prob = 1.0f / (1.0f + expf(-x));
        float neg  = 0.75f * (prob * prob) * (-log1pf(1e-8f - prob));
        float pos  = 0.25f * ((1.0f - prob) * (1.0f - prob)) * (-logf(prob + 1e-8f));
        float cls  = pos - neg;

        float l1 = fabsf(pb.x / im.x - tnx) + fabsf(pb.y / im.y - tny)
                 + fabsf(pb.z / im.z - tnz) + fabsf(pb.w / im.w - tnw);

        float area_a = (pb.z - pb.x) * (pb.w - pb.y);
        float ltx = fmaxf(pb.x, tb.x), lty = fmaxf(pb.y, tb.y);
        float rbx = fminf(pb.z, tb.z), rby = fminf(pb.w, tb.w);
        float iw = fmaxf(rbx - ltx, 0.0f), ih = fmaxf(rby - lty, 0.0f);
        float inter = iw * ih;
        float uni   = area_a + area_b - inter;
        float iou   = inter / uni;
        float ex1 = fminf(pb.x, tb.x), ey1 = fminf(pb.y, tb.y);
        float ex2 = fmaxf(pb.z, tb.z), ey2 = fmaxf(pb.w, tb.w);
        float ew = fmaxf(ex2 - ex1, 0.0f), eh = fmaxf(ey2 - ey1, 0.0f);
        float enc = ew * eh;
        float giou = iou - (enc - uni) / enc;

        float cost = 5.0f * l1 + 2.0f * cls + 2.0f * (-giou);
        Cout[(size_t)(b * QN + q) * TN + lane] = cost;
        colmin = kmin(colmin, ((ull)fkey(cost) << 32) | (unsigned)(q * TN + lane));
    }

    if (table) {
        __shared__ ull pk[4][TN];
        pk[wave][lane] = colmin;
        __syncthreads();
        if (wave == 0) {
            ull k = kmin(kmin(pk[0][lane], pk[1][lane]),
                         kmin(pk[2][lane], pk[3][lane]));
            atomicMin(&table[(size_t)b * TN + lane], k);   // device-scope
        }
    }
}

// ---------------------------------------------------------------------------
// Greedy hot loop (single wave; lane = column). m1[j] = min alive key of
// column j. Per iteration: dual DPP reduction (min value, then min flat among
// value-ties) == exact raveled argmin incl. first-occurrence tie-break.
// Champion-row death -> cooperative column rescan (expected ~4.4 per image).
// ---------------------------------------------------------------------------
__device__ __forceinline__ void greedy_loop(
    const float* __restrict__ Cb, ull m1, int b, int lane,
    float* __restrict__ out_rows, float* __restrict__ out_cols)
{
    // row-dead bitmask (wave-uniform, static indices); rows 500..511
    // (rescan over-range, reads stay inside d_out) pre-marked dead.
    ull rowdead[8];
    #pragma unroll
    for (int w = 0; w < 8; ++w) rowdead[w] = 0ull;
    rowdead[7] = 0xFFF0000000000000ull;

    int my_i = 0, my_j = 0;             // lane t captures iteration t's result

    for (int t = 0; t < TN; ++t) {
        const unsigned hi = (unsigned)(m1 >> 32);
        const unsigned bv = wave_min_u32(hi);              // min value (uniform)
        const unsigned fl = (hi == bv) ? (unsigned)m1 : 0xFFFFFFFFu;
        const unsigned flat = wave_min_u32(fl);            // min flat among ties
        const int i = (int)(flat >> 6);
        const int j = (int)(flat & 63u);
        if (lane == t) { my_i = i; my_j = j; }

        if (lane == j) m1 = ~0ull;                         // retire column
        #pragma unroll
        for (int w = 0; w < 8; ++w)                        // retire row
            if ((i >> 6) == w) rowdead[w] |= (1ull << (i & 63));

        // stale champions (argmin row == i) rescan; INF m1 auto-excluded
        // (low32=0xFFFFFFFF -> argrow 0x3FFFFFF never equals i<=511).
        ull need = __ballot((((unsigned)m1) >> 6) == (unsigned)i);
        while (need) {                                     // ~4.4 total/image
            const int jr = (int)(__ffsll((long long)need) - 1);  // lane==column
            need &= need - 1;
            ull nb = ~0ull;
            #pragma unroll
            for (int k8 = 0; k8 < 8; ++k8) {
                int r = lane + (k8 << 6);
                float vv = Cb[(size_t)r * TN + jr];
                bool dead = (rowdead[k8] >> lane) & 1ull;
                ull kk = dead ? ~0ull
                              : (((ull)fkey(vv) << 32) | (unsigned)(r * TN + jr));
                nb = kmin(nb, kk);
            }
            const unsigned nhi = (unsigned)(nb >> 32);
            const unsigned bhi = wave_min_u32(nhi);
            const unsigned nlo = (nhi == bhi) ? (unsigned)nb : 0xFFFFFFFFu;
            const unsigned blo = wave_min_u32(nlo);
            if (lane == jr) m1 = ((ull)bhi << 32) | blo;
        }
    }

    out_rows[b * TN + lane] = (float)my_i;                 // coalesced
    out_cols[b * TN + lane] = (float)my_j;
}

// Table path: single wave per image; init is ONE load per lane.
__global__ __launch_bounds__(64, 1) void assign_table_kernel(
    const float* __restrict__ Cmat, const ull* __restrict__ table,
    float* __restrict__ out_rows, float* __restrict__ out_cols)
{
    const int b = blockIdx.x, lane = threadIdx.x;
    greedy_loop(Cmat + (size_t)b * QN * TN, table[(size_t)b * TN + lane],
                b, lane, out_rows, out_cols);
}

// Fallback path (no workspace): float4 init, branchless min, LDS merge.
// Wave w, lane l: g=l>>4 owns rows w*63+g+4k (k<16), c4=l&15 owns cols
// [4c4,4c4+4) -> 16 independent float4 loads/thread (16 B/lane coalesced).
// Row over-coverage (waves overlap at 504>=r>=500 masked) is min-idempotent.
__global__ __launch_bounds__(512, 1) void assign_scan_kernel(
    const float* __restrict__ Cmat,
    float* __restrict__ out_rows, float* __restrict__ out_cols)
{
    const int b    = blockIdx.x;
    const int wave = threadIdx.x >> 6;
    const int lane = threadIdx.x & 63;
    const float* Cb = Cmat + (size_t)b * QN * TN;

    __shared__ ull smin[32][TN];        // 16 KB

    {
        const int g  = lane >> 4;
        const int c4 = (lane & 15) << 2;
        const int rbeg = wave * 63 + g;
        ull mc0 = ~0ull, mc1 = ~0ull, mc2 = ~0ull, mc3 = ~0ull;
        #pragma unroll
        for (int k = 0; k < 16; ++k) {
            const int r = rbeg + 4 * k;            // <= 504: inside d_out
            const float4 v = *(const float4*)(Cb + (size_t)r * TN + c4);
            const bool ok = (r < QN);
            const unsigned fb = (unsigned)(r * TN + c4);
            mc0 = kmin(mc0, ok ? (((ull)fkey(v.x) << 32) | (fb + 0)) : ~0ull);
            mc1 = kmin(mc1, ok ? (((ull)fkey(v.y) << 32) | (fb + 1)) : ~0ull);
            mc2 = kmin(mc2, ok ? (((ull)fkey(v.z) << 32) | (fb + 2)) : ~0ull);
            mc3 = kmin(mc3, ok ? (((ull)fkey(v.w) << 32) | (fb + 3)) : ~0ull);
        }
        const int lrow = (wave << 2) | g;
        smin[lrow][c4 + 0] = mc0;
        smin[lrow][c4 + 1] = mc1;
        smin[lrow][c4 + 2] = mc2;
        smin[lrow][c4 + 3] = mc3;
    }
    __syncthreads();
    if (wave != 0) return;

    ull m1 = ~0ull;
    #pragma unroll
    for (int w = 0; w < 32; ++w) m1 = kmin(m1, smin[w][lane]);

    greedy_loop(Cb, m1, b, lane, out_rows, out_cols);
}

extern "C" void kernel_launch(void* const* d_in, const int* in_sizes, int n_in,
                              void* d_out, int out_size, void* d_ws, size_t ws_size,
                              hipStream_t stream) {
    const float* logits = (const float*)d_in[0];   // [128,500,80]
    const float* boxes  = (const float*)d_in[1];   // [128,500,4]
    const int*   ids    = (const int*)d_in[2];     // [128,64]
    const float* tboxes = (const float*)d_in[3];   // [128,64,4]
    const float* img    = (const float*)d_in[4];   // [128,4]

    float* out  = (float*)d_out;
    float* Cmat = out;                              // 128*500*64 = 4,096,000
    float* rows = out + (size_t)BN * QN * TN;       // +8192
    float* cols = rows + BN * TN;                   // +8192

    const size_t table_bytes = (size_t)BN * TN * sizeof(ull);   // 64 KB
    const bool use_table = (ws_size >= table_bytes);            // host-constant
    ull* table = use_table ? (ull*)d_ws : nullptr;

    if (use_table)
        table_init_kernel<<<BN * TN / 256, 256, 0, stream>>>(table);

    cost_kernel<<<BN * CBI, 256, 0, stream>>>(logits, boxes, ids, tboxes, img,
                                              Cmat, table);

    if (use_table)
        assign_table_kernel<<<BN, 64, 0, stream>>>(Cmat, table, rows, cols);
    else
        assign_scan_kernel<<<BN, 512, 0, stream>>>(Cmat, rows, cols);
}

// Round 10
// 142.888 us; speedup vs baseline: 1.4024x; 1.0268x over previous
//
#include <hip/hip_runtime.h>

// Problem constants (from reference setup_inputs): B=128, Q=500, C=80, T=64
#define BN 128
#define QN 500
#define CLS 80
#define TN 64
#define RPB 20                  // rows per cost block
#define CBI 25                  // cost blocks per image (500/20)
#define RPW 5                   // rows per wave (RPB/4), compile-time trip

typedef unsigned long long ull;

// Monotonic float->uint map: a < b  <=>  fkey(a) < fkey(b); equal <=> equal
__device__ __forceinline__ unsigned fkey(float x) {
    unsigned u = __float_as_uint(x);
    return (u & 0x80000000u) ? ~u : (u | 0x80000000u);
}
__device__ __forceinline__ ull kmin(ull a, ull b) { return a < b ? a : b; }  // branchless

// Full-wave (64-lane) u32 min via DPP: row_shr 1/2/4/8 + row_bcast15/31,
// identity 0xFFFFFFFF fed to invalid lanes; result in lane 63 -> readlane.
#define DPP_MIN_STEP(v, ctrl)                                                 \
    {                                                                         \
        unsigned _t = (unsigned)__builtin_amdgcn_update_dpp(                  \
            (int)0xFFFFFFFF, (int)(v), (ctrl), 0xf, 0xf, false);              \
        (v) = (_t < (v)) ? _t : (v);                                          \
    }
__device__ __forceinline__ unsigned wave_min_u32(unsigned v) {
    DPP_MIN_STEP(v, 0x111)   // row_shr:1
    DPP_MIN_STEP(v, 0x112)   // row_shr:2
    DPP_MIN_STEP(v, 0x114)   // row_shr:4
    DPP_MIN_STEP(v, 0x118)   // row_shr:8
    DPP_MIN_STEP(v, 0x142)   // row_bcast:15
    DPP_MIN_STEP(v, 0x143)   // row_bcast:31
    return (unsigned)__builtin_amdgcn_readlane((int)v, 63);
}

// ---------------------------------------------------------------------------
// Kernel 1: cost matrix — per-element math BYTE-IDENTICAL to rounds 4/6/8/9
// (expf, log1pf, logf, true divisions; fast-math flips greedy ties -> round-5
// failure). Restructured for latency hiding: wave owns exactly RPW=5 rows
// (compile-time trip, #pragma unroll -> all 5 logit gathers + 5 box loads in
// flight at once; round 7/9 showed the rolled loop was gather-latency-bound
// at VALUBusy 21%). Block emits 64 colmin keys via PLAIN store into its own
// partial slot (no atomics -> no init kernel, no contention).
// ---------------------------------------------------------------------------
__global__ __launch_bounds__(256) void cost_kernel(
    const float* __restrict__ logits,   // [B,Q,C]
    const float* __restrict__ boxes,    // [B,Q,4]
    const int*   __restrict__ ids,      // [B,T]
    const float* __restrict__ tboxes,   // [B,T,4]
    const float* __restrict__ img,      // [B,4]
    float* __restrict__ Cout,           // [B,Q,T]
    ull* __restrict__ partial)          // [B*CBI, 64] colmin keys, or null
{
    const int b    = blockIdx.x / CBI;
    const int blk  = blockIdx.x % CBI;
    const int wave = threadIdx.x >> 6;
    const int lane = threadIdx.x & 63;   // = column t
    const int q0   = blk * RPB + wave * RPW;

    const float4 tb = *(const float4*)(tboxes + (size_t)(b * TN + lane) * 4);
    const float4 im = *(const float4*)(img + b * 4);
    const int    id = ids[b * TN + lane];
    const float tnx = tb.x / im.x, tny = tb.y / im.y;
    const float tnz = tb.z / im.z, tnw = tb.w / im.w;
    const float area_b = (tb.z - tb.x) * (tb.w - tb.y);

    ull colmin = ~0ull;
    #pragma unroll
    for (int rr = 0; rr < RPW; ++rr) {
        const int q = q0 + rr;
        const float4 pb = *(const float4*)(boxes + (size_t)(b * QN + q) * 4);
        const float x   = logits[(size_t)(b * QN + q) * CLS + id];

        float prob = 1.0f / (1.0f + expf(-x));
        float neg  = 0.75f * (prob * prob) * (-log1pf(1e-8f - prob));
        float pos  = 0.25f * ((1.0f - prob) * (1.0f - prob)) * (-logf(prob + 1e-8f));
        float cls  = pos - neg;

        float l1 = fabsf(pb.x / im.x - tnx) + fabsf(pb.y / im.y - tny)
                 + fabsf(pb.z / im.z - tnz) + fabsf(pb.w / im.w - tnw);

        float area_a = (pb.z - pb.x) * (pb.w - pb.y);
        float ltx = fmaxf(pb.x, tb.x), lty = fmaxf(pb.y, tb.y);
        float rbx = fminf(pb.z, tb.z), rby = fminf(pb.w, tb.w);
        float iw = fmaxf(rbx - ltx, 0.0f), ih = fmaxf(rby - lty, 0.0f);
        float inter = iw * ih;
        float uni   = area_a + area_b - inter;
        float iou   = inter / uni;
        float ex1 = fminf(pb.x, tb.x), ey1 = fminf(pb.y, tb.y);
        float ex2 = fmaxf(pb.z, tb.z), ey2 = fmaxf(pb.w, tb.w);
        float ew = fmaxf(ex2 - ex1, 0.0f), eh = fmaxf(ey2 - ey1, 0.0f);
        float enc = ew * eh;
        float giou = iou - (enc - uni) / enc;

        float cost = 5.0f * l1 + 2.0f * cls + 2.0f * (-giou);
        Cout[(size_t)(b * QN + q) * TN + lane] = cost;
        colmin = kmin(colmin, ((ull)fkey(cost) << 32) | (unsigned)(q * TN + lane));
    }

    if (partial) {
        __shared__ ull pk[4][TN];
        pk[wave][lane] = colmin;
        __syncthreads();
        if (wave == 0) {
            ull k = kmin(kmin(pk[0][lane], pk[1][lane]),
                         kmin(pk[2][lane], pk[3][lane]));
            partial[(size_t)blockIdx.x * TN + lane] = k;   // own slot: no race
        }
    }
}

// ---------------------------------------------------------------------------
// Greedy hot loop (single wave; lane = column). m1[j] = min alive key of
// column j. Per iteration: dual DPP reduction (min value, then min flat among
// value-ties) == exact raveled argmin incl. first-occurrence tie-break.
// Champion-row death -> cooperative column rescan (expected ~4.6 per image).
// ---------------------------------------------------------------------------
__device__ __forceinline__ void greedy_loop(
    const float* __restrict__ Cb, ull m1, int b, int lane,
    float* __restrict__ out_rows, float* __restrict__ out_cols)
{
    // row-dead bitmask (wave-uniform, static indices); rows 500..511
    // (rescan over-range, reads stay inside d_out) pre-marked dead.
    ull rowdead[8];
    #pragma unroll
    for (int w = 0; w < 8; ++w) rowdead[w] = 0ull;
    rowdead[7] = 0xFFF0000000000000ull;

    int my_i = 0, my_j = 0;             // lane t captures iteration t's result

    for (int t = 0; t < TN; ++t) {
        const unsigned hi = (unsigned)(m1 >> 32);
        const unsigned bv = wave_min_u32(hi);              // min value (uniform)
        const unsigned fl = (hi == bv) ? (unsigned)m1 : 0xFFFFFFFFu;
        const unsigned flat = wave_min_u32(fl);            // min flat among ties
        const int i = (int)(flat >> 6);
        const int j = (int)(flat & 63u);
        if (lane == t) { my_i = i; my_j = j; }

        if (lane == j) m1 = ~0ull;                         // retire column
        #pragma unroll
        for (int w = 0; w < 8; ++w)                        // retire row
            if ((i >> 6) == w) rowdead[w] |= (1ull << (i & 63));

        // stale champions (argmin row == i) rescan; INF m1 auto-excluded
        // (low32=0xFFFFFFFF -> argrow 0x3FFFFFF never equals i<=511).
        ull need = __ballot((((unsigned)m1) >> 6) == (unsigned)i);
        while (need) {                                     // ~4.6 total/image
            const int jr = (int)(__ffsll((long long)need) - 1);  // lane==column
            need &= need - 1;
            ull nb = ~0ull;
            #pragma unroll
            for (int k8 = 0; k8 < 8; ++k8) {
                int r = lane + (k8 << 6);
                float vv = Cb[(size_t)r * TN + jr];
                bool dead = (rowdead[k8] >> lane) & 1ull;
                ull kk = dead ? ~0ull
                              : (((ull)fkey(vv) << 32) | (unsigned)(r * TN + jr));
                nb = kmin(nb, kk);
            }
            const unsigned nhi = (unsigned)(nb >> 32);
            const unsigned bhi = wave_min_u32(nhi);
            const unsigned nlo = (nhi == bhi) ? (unsigned)nb : 0xFFFFFFFFu;
            const unsigned blo = wave_min_u32(nlo);
            if (lane == jr) m1 = ((ull)bhi << 32) | blo;
        }
    }

    out_rows[b * TN + lane] = (float)my_i;                 // coalesced
    out_cols[b * TN + lane] = (float)my_j;
}

// Table path: 512 threads; 8 waves cooperatively reduce the image's 25
// partial rows (coalesced 512 B row loads), LDS merge, wave 0 runs greedy.
__global__ __launch_bounds__(512, 1) void assign_table_kernel(
    const float* __restrict__ Cmat, const ull* __restrict__ partial,
    float* __restrict__ out_rows, float* __restrict__ out_cols)
{
    const int b    = blockIdx.x;
    const int wave = threadIdx.x >> 6;
    const int lane = threadIdx.x & 63;
    const float* Cb = Cmat + (size_t)b * QN * TN;
    const ull* pt = partial + (size_t)b * CBI * TN;

    __shared__ ull smin[8][TN];         // 4 KB
    {
        ull k = ~0ull;
        #pragma unroll
        for (int p = 0; p < 4; ++p) {   // rows wave, wave+8, wave+16, wave+24
            const int row = wave + 8 * p;
            if (row < CBI) k = kmin(k, pt[(size_t)row * TN + lane]);
        }
        smin[wave][lane] = k;
    }
    __syncthreads();
    if (wave != 0) return;

    ull m1 = ~0ull;
    #pragma unroll
    for (int w = 0; w < 8; ++w) m1 = kmin(m1, smin[w][lane]);

    greedy_loop(Cb, m1, b, lane, out_rows, out_cols);
}

// Fallback path (no workspace): float4 init, branchless min, LDS merge.
// Wave w, lane l: g=l>>4 owns rows w*63+g+4k (k<16), c4=l&15 owns cols
// [4c4,4c4+4) -> 16 independent float4 loads/thread. Proven in round 9.
__global__ __launch_bounds__(512, 1) void assign_scan_kernel(
    const float* __restrict__ Cmat,
    float* __restrict__ out_rows, float* __restrict__ out_cols)
{
    const int b    = blockIdx.x;
    const int wave = threadIdx.x >> 6;
    const int lane = threadIdx.x & 63;
    const float* Cb = Cmat + (size_t)b * QN * TN;

    __shared__ ull smin[32][TN];        // 16 KB

    {
        const int g  = lane >> 4;
        const int c4 = (lane & 15) << 2;
        const int rbeg = wave * 63 + g;
        ull mc0 = ~0ull, mc1 = ~0ull, mc2 = ~0ull, mc3 = ~0ull;
        #pragma unroll
        for (int k = 0; k < 16; ++k) {
            const int r = rbeg + 4 * k;            // <= 504: inside d_out
            const float4 v = *(const float4*)(Cb + (size_t)r * TN + c4);
            const bool ok = (r < QN);
            const unsigned fb = (unsigned)(r * TN + c4);
            mc0 = kmin(mc0, ok ? (((ull)fkey(v.x) << 32) | (fb + 0)) : ~0ull);
            mc1 = kmin(mc1, ok ? (((ull)fkey(v.y) << 32) | (fb + 1)) : ~0ull);
            mc2 = kmin(mc2, ok ? (((ull)fkey(v.z) << 32) | (fb + 2)) : ~0ull);
            mc3 = kmin(mc3, ok ? (((ull)fkey(v.w) << 32) | (fb + 3)) : ~0ull);
        }
        const int lrow = (wave << 2) | g;
        smin[lrow][c4 + 0] = mc0;
        smin[lrow][c4 + 1] = mc1;
        smin[lrow][c4 + 2] = mc2;
        smin[lrow][c4 + 3] = mc3;
    }
    __syncthreads();
    if (wave != 0) return;

    ull m1 = ~0ull;
    #pragma unroll
    for (int w = 0; w < 32; ++w) m1 = kmin(m1, smin[w][lane]);

    greedy_loop(Cb, m1, b, lane, out_rows, out_cols);
}

extern "C" void kernel_launch(void* const* d_in, const int* in_sizes, int n_in,
                              void* d_out, int out_size, void* d_ws, size_t ws_size,
                              hipStream_t stream) {
    const float* logits = (const float*)d_in[0];   // [128,500,80]
    const float* boxes  = (const float*)d_in[1];   // [128,500,4]
    const int*   ids    = (const int*)d_in[2];     // [128,64]
    const float* tboxes = (const float*)d_in[3];   // [128,64,4]
    const float* img    = (const float*)d_in[4];   // [128,4]

    float* out  = (float*)d_out;
    float* Cmat = out;                              // 128*500*64 = 4,096,000
    float* rows = out + (size_t)BN * QN * TN;       // +8192
    float* cols = rows + BN * TN;                   // +8192

    const size_t table_bytes = (size_t)BN * CBI * TN * sizeof(ull);  // 1.6 MB
    const bool use_table = (ws_size >= table_bytes);                  // host-constant
    ull* partial = use_table ? (ull*)d_ws : nullptr;

    cost_kernel<<<BN * CBI, 256, 0, stream>>>(logits, boxes, ids, tboxes, img,
                                              Cmat, partial);

    if (use_table)
        assign_table_kernel<<<BN, 512, 0, stream>>>(Cmat, partial, rows, cols);
    else
        assign_scan_kernel<<<BN, 512, 0, stream>>>(Cmat, rows, cols);
}